// Round 9
// baseline (373.953 us; speedup 1.0000x reference)
//
#include <hip/hip_runtime.h>
#include <hip/hip_bf16.h>

#define N_NODES 100000
#define D_IN 128
#define D_H 256
#define D_E 64
#define MT 32        // nodes per GEMM block
#define BSHIFT 9                                   // 512 nodes per bucket
#define NBUCK ((N_NODES + 511) >> BSHIFT)          // 196
#define CHUNK 8192                                 // edges per pass-1 block
#define RCR_T 1024                                 // pass-1 threads
#define RCR_ILP (CHUNK / RCR_T)                    // 8 edges per thread

typedef __attribute__((ext_vector_type(8))) short short8;
typedef __attribute__((ext_vector_type(4))) float floatx4;

__device__ inline unsigned short f2bf(float f) {
    union { float f; unsigned u; } v; v.f = f;
    unsigned r = v.u + 0x7FFF + ((v.u >> 16) & 1);
    return (unsigned short)(r >> 16);
}
__device__ inline unsigned f2bf2(float a, float b) {
    return (unsigned)f2bf(a) | ((unsigned)f2bf(b) << 16);
}
__device__ inline float2 bf2f2(unsigned v) {
    union { unsigned u; float f; } lo, hi;
    lo.u = v << 16;
    hi.u = v & 0xffff0000u;
    return make_float2(lo.f, hi.f);  // .x = lower-address bf16
}

#define MFMA16(a, b, c) __builtin_amdgcn_mfma_f32_16x16x32_bf16((a), (b), (c), 0, 0, 0)

// ---------------- weight pre-pack to bf16, SWIZZLED to MFMA fragment order ----
__global__ void convert_weights(const float* __restrict__ Wl1, const float* __restrict__ Wr1,
                                const float* __restrict__ Wl2, const float* __restrict__ Wr2,
                                const float* __restrict__ fc1W, const float* __restrict__ fc2W,
                                unsigned short* __restrict__ W1s, unsigned short* __restrict__ W2s,
                                unsigned short* __restrict__ F1s, unsigned short* __restrict__ F2s) {
    int idx = blockIdx.x * blockDim.x + threadIdx.x;
    if (idx < 65536) {
        int out = idx >> 8, k = idx & 255;
        float v = (k < 128) ? Wl1[out * 128 + k] : Wr1[out * 128 + (k - 128)];
        int ks = k >> 5, quad = (k >> 3) & 3, e = k & 7, col = out & 15;
        int g = (out >> 4) * 8 + ks;
        W1s[(g * 64 + quad * 16 + col) * 8 + e] = f2bf(v);
    } else if (idx < 98304) {
        int i = idx - 65536; int out = i >> 8, k = i & 255;
        float v = (out < 64) ? Wl2[out * 256 + k] : Wr2[(out - 64) * 256 + k];
        int ks = k >> 5, quad = (k >> 3) & 3, e = k & 7, col = out & 15;
        int g = (out >> 4) * 8 + ks;
        W2s[(g * 64 + quad * 16 + col) * 8 + e] = f2bf(v);
    } else if (idx < 114688) {
        int i = idx - 98304;
        int out = i >> 6, k = i & 63;
        float v = fc1W[i];
        int ks = k >> 5, quad = (k >> 3) & 3, e = k & 7, col = out & 15;
        int g = (out >> 4) * 2 + ks;
        F1s[(g * 64 + quad * 16 + col) * 8 + e] = f2bf(v);
    } else if (idx < 147456) {
        int i = idx - 114688;
        int out = i >> 8, k = i & 255;
        float v = fc2W[i];
        int ks = k >> 5, quad = (k >> 3) & 3, e = k & 7, col = out & 15;
        int g = (out >> 4) * 8 + ks;
        F2s[(g * 64 + quad * 16 + col) * 8 + e] = f2bf(v);
    }
}

// x fp32 -> bf16 (packed pairs)
__global__ void convert_x(const float4* __restrict__ x4, uint2* __restrict__ xbf2, int total4) {
    int idx = blockIdx.x * blockDim.x + threadIdx.x;
    if (idx >= total4) return;
    float4 v = x4[idx];
    uint2 o;
    o.x = f2bf2(v.x, v.y);
    o.y = f2bf2(v.z, v.w);
    xbf2[idx] = o;
}

// ---------------- bucket-level histogram ----------
__global__ __launch_bounds__(RCR_T) void bucket_hist(
        const int* __restrict__ dst, int* __restrict__ bucketCnt, int E) {
    __shared__ int hist[256];
    const int t = threadIdx.x;
    if (t < 256) hist[t] = 0;
    __syncthreads();
    const int e0 = blockIdx.x * CHUNK;
    if (e0 + CHUNK <= E) {
        int dv[RCR_ILP];
#pragma unroll
        for (int i = 0; i < RCR_ILP; i++) dv[i] = dst[e0 + t + i * RCR_T];
#pragma unroll
        for (int i = 0; i < RCR_ILP; i++) atomicAdd(&hist[dv[i] >> BSHIFT], 1);
    } else {
        for (int e = e0 + t; e < E; e += RCR_T)
            atomicAdd(&hist[dst[e] >> BSHIFT], 1);
    }
    __syncthreads();
    if (t < NBUCK && hist[t] > 0) atomicAdd(&bucketCnt[t * 16], hist[t]);
}

// single-block exclusive scan of 196 bucket counts -> bucketOffs[0..196]
__global__ void bucket_scan(const int* __restrict__ bucketCnt,
                            int* __restrict__ bucketOffs) {
    __shared__ int s[256];
    int t = threadIdx.x;
    int v = (t < NBUCK) ? bucketCnt[t * 16] : 0;
    s[t] = v;
    __syncthreads();
    for (int off = 1; off < 256; off <<= 1) {
        int tv = (t >= off) ? s[t - off] : 0;
        __syncthreads();
        s[t] += tv;
        __syncthreads();
    }
    if (t < NBUCK) bucketOffs[t] = s[t] - v;
    if (t == NBUCK - 1) bucketOffs[NBUCK] = s[t];
}

// ---------------- two-pass radix partition (per-block reservation) ----------
__global__ __launch_bounds__(RCR_T) void radix_count_reserve(
        const int* __restrict__ src, const int* __restrict__ dst,
        const int* __restrict__ bucketOffs, int* __restrict__ gcur,
        unsigned* __restrict__ pairs, int E) {
    __shared__ int hist[256];
    __shared__ int sBase[256];
    __shared__ int sCur[256];
    const int t = threadIdx.x;
    if (t < 256) { hist[t] = 0; sCur[t] = 0; }
    __syncthreads();
    const int e0 = blockIdx.x * CHUNK;

    if (e0 + CHUNK <= E) {
        int dv[RCR_ILP], sv[RCR_ILP];
#pragma unroll
        for (int i = 0; i < RCR_ILP; i++) dv[i] = dst[e0 + t + i * RCR_T];
#pragma unroll
        for (int i = 0; i < RCR_ILP; i++) atomicAdd(&hist[dv[i] >> BSHIFT], 1);
        __syncthreads();
        if (t < NBUCK && hist[t] > 0)
            sBase[t] = bucketOffs[t] + atomicAdd(&gcur[t * 16], hist[t]);
        __syncthreads();
#pragma unroll
        for (int i = 0; i < RCR_ILP; i++) sv[i] = src[e0 + t + i * RCR_T];
#pragma unroll
        for (int i = 0; i < RCR_ILP; i++) {
            int d = dv[i];
            int b = d >> BSHIFT;
            int pos = sBase[b] + atomicAdd(&sCur[b], 1);
            pairs[pos] = (unsigned)sv[i] | ((unsigned)(d & 511) << 20);
        }
    } else {
        const int e1 = E;
        for (int e = e0 + t; e < e1; e += RCR_T)
            atomicAdd(&hist[dst[e] >> BSHIFT], 1);
        __syncthreads();
        if (t < NBUCK && hist[t] > 0)
            sBase[t] = bucketOffs[t] + atomicAdd(&gcur[t * 16], hist[t]);
        __syncthreads();
        for (int e = e0 + t; e < e1; e += RCR_T) {
            int d = dst[e];
            int b = d >> BSHIFT;
            int pos = sBase[b] + atomicAdd(&sCur[b], 1);
            pairs[pos] = (unsigned)src[e] | ((unsigned)(d & 511) << 20);
        }
    }
}

// Pass 2: one WG per bucket. LDS-histogram the 512 local dst's, LDS scan ->
// write degI/offs directly, then scatter into the bucket's srcS window.
__global__ __launch_bounds__(512) void radix_scatter2(
        const unsigned* __restrict__ pairs, const int* __restrict__ bucketOffs,
        int* __restrict__ degI, int* __restrict__ offs,
        int* __restrict__ srcS) {
    __shared__ int sCnt[512];
    __shared__ int sOff[512];
    const int b = blockIdx.x;
    const int lo = b << BSHIFT;
    const int t = threadIdx.x;
    sCnt[t] = 0;
    __syncthreads();
    const int start = bucketOffs[b];
    const int end = bucketOffs[b + 1];
    for (int i = start + t; i < end; i += 512)
        atomicAdd(&sCnt[pairs[i] >> 20], 1);
    __syncthreads();
    int v = sCnt[t];
    sOff[t] = v;
    __syncthreads();
    for (int off = 1; off < 512; off <<= 1) {
        int tv = (t >= off) ? sOff[t - off] : 0;
        __syncthreads();
        sOff[t] += tv;
        __syncthreads();
    }
    int excl = sOff[t] - v;
    int node = lo + t;
    if (node < N_NODES) {
        degI[node] = v;
        offs[node] = start + excl;
    }
    __syncthreads();
    sCnt[t] = start + excl;
    __syncthreads();
    int i = start + t;
    for (; i + 3 * 512 < end; i += 4 * 512) {
        unsigned p0 = pairs[i];
        unsigned p1 = pairs[i + 512];
        unsigned p2 = pairs[i + 1024];
        unsigned p3 = pairs[i + 1536];
        int dl0 = (int)(p0 >> 20), dl1 = (int)(p1 >> 20);
        int dl2 = (int)(p2 >> 20), dl3 = (int)(p3 >> 20);
        int q0 = atomicAdd(&sCnt[dl0], 1);
        int q1 = atomicAdd(&sCnt[dl1], 1);
        int q2 = atomicAdd(&sCnt[dl2], 1);
        int q3 = atomicAdd(&sCnt[dl3], 1);
        srcS[q0] = (int)(p0 & 0xFFFFFu);
        srcS[q1] = (int)(p1 & 0xFFFFFu);
        srcS[q2] = (int)(p2 & 0xFFFFFu);
        srcS[q3] = (int)(p3 & 0xFFFFFu);
    }
    for (; i < end; i += 512) {
        unsigned p = pairs[i];
        int dl = (int)(p >> 20);
        int pos = atomicAdd(&sCnt[dl], 1);
        srcS[pos] = (int)(p & 0xFFFFFu);
    }
}

// ---------------- gather: mean of bf16 x rows -> packed bf16 mean ------------
// one wave per node, QUARTER-WAVE per edge: 16 lanes x uint4 (16B) = 256B row.
// 32 edges / 8 gather-loads in flight per main iteration (MLP-deep).
#define ACC8(v)                                                   \
    { float2 f_;                                                  \
      f_ = bf2f2((v).x); s0 += f_.x; s1 += f_.y;                  \
      f_ = bf2f2((v).y); s2 += f_.x; s3 += f_.y;                  \
      f_ = bf2f2((v).z); s4 += f_.x; s5 += f_.y;                  \
      f_ = bf2f2((v).w); s6 += f_.x; s7 += f_.y; }

__global__ __launch_bounds__(256) void gather_mean_bf(
        const uint4* __restrict__ xb4, const int* __restrict__ srcS,
        const int* __restrict__ offs, const int* __restrict__ degI,
        uint4* __restrict__ mean4) {
    const int wave = threadIdx.x >> 6, lane = threadIdx.x & 63;
    const int n = blockIdx.x * 4 + wave;
    if (n >= N_NODES) return;
    const int start = offs[n], cnt = degI[n];
    const int* sp = srcS + start;
    const int q = lane >> 4, l16 = lane & 15;
    float s0 = 0.f, s1 = 0.f, s2 = 0.f, s3 = 0.f;
    float s4 = 0.f, s5 = 0.f, s6 = 0.f, s7 = 0.f;
    int j = 0;
    for (; j + 32 <= cnt; j += 32) {
        int i0 = sp[j + q],      i1 = sp[j + 4 + q];
        int i2 = sp[j + 8 + q],  i3 = sp[j + 12 + q];
        int i4 = sp[j + 16 + q], i5 = sp[j + 20 + q];
        int i6 = sp[j + 24 + q], i7 = sp[j + 28 + q];
        uint4 v0 = xb4[i0 * 16 + l16];
        uint4 v1 = xb4[i1 * 16 + l16];
        uint4 v2 = xb4[i2 * 16 + l16];
        uint4 v3 = xb4[i3 * 16 + l16];
        uint4 v4 = xb4[i4 * 16 + l16];
        uint4 v5 = xb4[i5 * 16 + l16];
        uint4 v6 = xb4[i6 * 16 + l16];
        uint4 v7 = xb4[i7 * 16 + l16];
        ACC8(v0); ACC8(v1); ACC8(v2); ACC8(v3);
        ACC8(v4); ACC8(v5); ACC8(v6); ACC8(v7);
    }
    for (; j + 4 <= cnt; j += 4) {
        uint4 v = xb4[sp[j + q] * 16 + l16];
        ACC8(v);
    }
    if (q < cnt - j) {
        uint4 v = xb4[sp[j + q] * 16 + l16];
        ACC8(v);
    }
    // cross-quarter reduction: lanes 0-15 end with full sums
    s0 += __shfl_down(s0, 32); s1 += __shfl_down(s1, 32);
    s2 += __shfl_down(s2, 32); s3 += __shfl_down(s3, 32);
    s4 += __shfl_down(s4, 32); s5 += __shfl_down(s5, 32);
    s6 += __shfl_down(s6, 32); s7 += __shfl_down(s7, 32);
    s0 += __shfl_down(s0, 16); s1 += __shfl_down(s1, 16);
    s2 += __shfl_down(s2, 16); s3 += __shfl_down(s3, 16);
    s4 += __shfl_down(s4, 16); s5 += __shfl_down(s5, 16);
    s6 += __shfl_down(s6, 16); s7 += __shfl_down(s7, 16);
    if (lane < 16) {
        float rd = 1.0f / fmaxf((float)cnt, 1.0f);
        uint4 o;
        o.x = f2bf2(s0 * rd, s1 * rd);
        o.y = f2bf2(s2 * rd, s3 * rd);
        o.z = f2bf2(s4 * rd, s5 * rd);
        o.w = f2bf2(s6 * rd, s7 * rd);
        mean4[n * 16 + l16] = o;
    }
}

// ---------------- layer1 MFMA: [mean|x] -> h -> [z2|r2] ----------------
__global__ __launch_bounds__(256, 4) void layer1_mfma(
        const unsigned* __restrict__ xbfu, const unsigned* __restrict__ meanbf,
        const unsigned short* __restrict__ W1s, const float* __restrict__ bl1,
        const unsigned short* __restrict__ W2s,
        unsigned short* __restrict__ z2bf, float* __restrict__ embOut) {
    __shared__ unsigned short sA[MT][264];
    __shared__ unsigned short sH[MT][264];
    const int tid = threadIdx.x;
    const int node0 = blockIdx.x * MT;

    const uint4* mean4 = (const uint4*)meanbf;
    const uint4* x4    = (const uint4*)xbfu;
#pragma unroll
    for (int it = 0; it < 4; it++) {
        int c = tid + it * 256;
        int row = c >> 5, half = (c >> 4) & 1, ci = c & 15;
        uint4 v = half ? x4[(node0 + row) * 16 + ci]
                       : mean4[(node0 + row) * 16 + ci];
        *(uint4*)&sA[row][half * 128 + ci * 8] = v;
    }
    __syncthreads();

    const int wave = tid >> 6, lane = tid & 63;
    const int col = lane & 15, quad = lane >> 4;

    // ---- phase A: h = relu(A @ W1^T + bl1), N=256, K=256 ----
    floatx4 acc[2][4];
    const floatx4 zero = {0.f, 0.f, 0.f, 0.f};
#pragma unroll
    for (int mt = 0; mt < 2; mt++)
#pragma unroll
        for (int nt = 0; nt < 4; nt++) acc[mt][nt] = zero;

    const short8* w1base = (const short8*)W1s + wave * 2048 + lane;
#pragma unroll
    for (int ks = 0; ks < 8; ks++) {
        short8 a0 = *(const short8*)&sA[col][ks * 32 + quad * 8];
        short8 a1 = *(const short8*)&sA[16 + col][ks * 32 + quad * 8];
#pragma unroll
        for (int nt = 0; nt < 4; nt++) {
            short8 b = w1base[(nt * 8 + ks) * 64];
            acc[0][nt] = MFMA16(a0, b, acc[0][nt]);
            acc[1][nt] = MFMA16(a1, b, acc[1][nt]);
        }
    }

#pragma unroll
    for (int nt = 0; nt < 4; nt++) {
        int out = (wave * 4 + nt) * 16 + col;
        float bias = bl1[out];
#pragma unroll
        for (int mt = 0; mt < 2; mt++)
#pragma unroll
            for (int r = 0; r < 4; r++)
                sH[mt * 16 + quad * 4 + r][out] = f2bf(fmaxf(acc[mt][nt][r] + bias, 0.f));
    }
    __syncthreads();

    // ---- phase B: [z2|r2] = h @ W2^T, N=128, K=256 ----
    floatx4 acc2[2][2];
#pragma unroll
    for (int mt = 0; mt < 2; mt++)
#pragma unroll
        for (int nt = 0; nt < 2; nt++) acc2[mt][nt] = zero;

    const short8* w2base = (const short8*)W2s + wave * 1024 + lane;
#pragma unroll
    for (int ks = 0; ks < 8; ks++) {
        short8 h0 = *(const short8*)&sH[col][ks * 32 + quad * 8];
        short8 h1 = *(const short8*)&sH[16 + col][ks * 32 + quad * 8];
#pragma unroll
        for (int nt = 0; nt < 2; nt++) {
            short8 b = w2base[(nt * 8 + ks) * 64];
            acc2[0][nt] = MFMA16(h0, b, acc2[0][nt]);
            acc2[1][nt] = MFMA16(h1, b, acc2[1][nt]);
        }
    }

#pragma unroll
    for (int nt = 0; nt < 2; nt++) {
        int out = (wave * 2 + nt) * 16 + col;
#pragma unroll
        for (int mt = 0; mt < 2; mt++)
#pragma unroll
            for (int r = 0; r < 4; r++) {
                int node = node0 + mt * 16 + quad * 4 + r;
                float v = acc2[mt][nt][r];
                if (out < 64) z2bf[node * 64 + out] = f2bf(v);
                else          embOut[node * 64 + (out - 64)] = v;
            }
    }
}

// ---------------- gather: emb = agg(z2)/deg + bl2 + r2 ----------------
// one wave per node, EIGHTH-WAVE per edge: 8 lanes x uint4 = 128B z2 row.
// 32 edges / 4 gather-loads in flight per main iteration.
__global__ __launch_bounds__(256) void gather_emb(
        const uint4* __restrict__ z4, const int* __restrict__ srcS,
        const int* __restrict__ offs, const int* __restrict__ degI,
        const float* __restrict__ bl2, float* __restrict__ emb,
        uint4* __restrict__ emb4) {
    const int wave = threadIdx.x >> 6, lane = threadIdx.x & 63;
    const int n = blockIdx.x * 4 + wave;
    if (n >= N_NODES) return;
    const int start = offs[n], cnt = degI[n];
    const int* sp = srcS + start;
    const int o8 = lane >> 3, l8 = lane & 7;
    float s0 = 0.f, s1 = 0.f, s2 = 0.f, s3 = 0.f;
    float s4 = 0.f, s5 = 0.f, s6 = 0.f, s7 = 0.f;
    int j = 0;
    for (; j + 32 <= cnt; j += 32) {
        int i0 = sp[j + o8],      i1 = sp[j + 8 + o8];
        int i2 = sp[j + 16 + o8], i3 = sp[j + 24 + o8];
        uint4 v0 = z4[i0 * 8 + l8];
        uint4 v1 = z4[i1 * 8 + l8];
        uint4 v2 = z4[i2 * 8 + l8];
        uint4 v3 = z4[i3 * 8 + l8];
        ACC8(v0); ACC8(v1); ACC8(v2); ACC8(v3);
    }
    for (; j + 8 <= cnt; j += 8) {
        uint4 v = z4[sp[j + o8] * 8 + l8];
        ACC8(v);
    }
    if (o8 < cnt - j) {
        uint4 v = z4[sp[j + o8] * 8 + l8];
        ACC8(v);
    }
    // cross-eighth reduction: lanes 0-7 end with full sums
    s0 += __shfl_down(s0, 32); s1 += __shfl_down(s1, 32);
    s2 += __shfl_down(s2, 32); s3 += __shfl_down(s3, 32);
    s4 += __shfl_down(s4, 32); s5 += __shfl_down(s5, 32);
    s6 += __shfl_down(s6, 32); s7 += __shfl_down(s7, 32);
    s0 += __shfl_down(s0, 16); s1 += __shfl_down(s1, 16);
    s2 += __shfl_down(s2, 16); s3 += __shfl_down(s3, 16);
    s4 += __shfl_down(s4, 16); s5 += __shfl_down(s5, 16);
    s6 += __shfl_down(s6, 16); s7 += __shfl_down(s7, 16);
    s0 += __shfl_down(s0, 8);  s1 += __shfl_down(s1, 8);
    s2 += __shfl_down(s2, 8);  s3 += __shfl_down(s3, 8);
    s4 += __shfl_down(s4, 8);  s5 += __shfl_down(s5, 8);
    s6 += __shfl_down(s6, 8);  s7 += __shfl_down(s7, 8);
    if (lane < 8) {
        float rd = 1.0f / fmaxf((float)cnt, 1.0f);
        float4 ra = *(const float4*)&emb[n * 64 + l8 * 8];
        float4 rb = *(const float4*)&emb[n * 64 + l8 * 8 + 4];
        float4 ba = *(const float4*)&bl2[l8 * 8];
        float4 bb = *(const float4*)&bl2[l8 * 8 + 4];
        float e0 = s0 * rd + ba.x + ra.x;
        float e1 = s1 * rd + ba.y + ra.y;
        float e2 = s2 * rd + ba.z + ra.z;
        float e3 = s3 * rd + ba.w + ra.w;
        float e4 = s4 * rd + bb.x + rb.x;
        float e5 = s5 * rd + bb.y + rb.y;
        float e6 = s6 * rd + bb.z + rb.z;
        float e7 = s7 * rd + bb.w + rb.w;
        float4 wa = {e0, e1, e2, e3};
        float4 wb = {e4, e5, e6, e7};
        *(float4*)&emb[n * 64 + l8 * 8] = wa;
        *(float4*)&emb[n * 64 + l8 * 8 + 4] = wb;
        uint4 o;
        o.x = f2bf2(e0, e1);
        o.y = f2bf2(e2, e3);
        o.z = f2bf2(e4, e5);
        o.w = f2bf2(e6, e7);
        emb4[n * 8 + l8] = o;
    }
}

// ---------------- decoder MFMA: emb -> hid -> recon ----------------
__global__ __launch_bounds__(256, 4) void decoder_mfma(
        const unsigned* __restrict__ embbf,
        const unsigned short* __restrict__ F1s, const float* __restrict__ fc1b,
        const unsigned short* __restrict__ F2s, const float* __restrict__ fc2b,
        float* __restrict__ recon) {
    __shared__ unsigned short sE[MT][72];
    __shared__ unsigned short sH[MT][264];
    const int tid = threadIdx.x;
    const int node0 = blockIdx.x * MT;

    {
        const uint4* e4 = (const uint4*)embbf;
        int row = tid >> 3, ci = tid & 7;
        *(uint4*)&sE[row][ci * 8] = e4[(node0 + row) * 8 + ci];
    }
    __syncthreads();

    const int wave = tid >> 6, lane = tid & 63;
    const int col = lane & 15, quad = lane >> 4;

    // ---- phase A: hid = relu(emb @ fc1^T + fc1b), N=256, K=64 ----
    floatx4 acc[2][4];
    const floatx4 zero = {0.f, 0.f, 0.f, 0.f};
#pragma unroll
    for (int mt = 0; mt < 2; mt++)
#pragma unroll
        for (int nt = 0; nt < 4; nt++) acc[mt][nt] = zero;

    const short8* f1base = (const short8*)F1s + wave * 512 + lane;
#pragma unroll
    for (int ks = 0; ks < 2; ks++) {
        short8 a0 = *(const short8*)&sE[col][ks * 32 + quad * 8];
        short8 a1 = *(const short8*)&sE[16 + col][ks * 32 + quad * 8];
#pragma unroll
        for (int nt = 0; nt < 4; nt++) {
            short8 b = f1base[(nt * 2 + ks) * 64];
            acc[0][nt] = MFMA16(a0, b, acc[0][nt]);
            acc[1][nt] = MFMA16(a1, b, acc[1][nt]);
        }
    }

#pragma unroll
    for (int nt = 0; nt < 4; nt++) {
        int out = (wave * 4 + nt) * 16 + col;
        float bias = fc1b[out];
#pragma unroll
        for (int mt = 0; mt < 2; mt++)
#pragma unroll
            for (int r = 0; r < 4; r++)
                sH[mt * 16 + quad * 4 + r][out] = f2bf(fmaxf(acc[mt][nt][r] + bias, 0.f));
    }
    __syncthreads();

    // ---- phase B: recon = hid @ fc2^T + fc2b, N=128, K=256 ----
    floatx4 acc2[2][2];
#pragma unroll
    for (int mt = 0; mt < 2; mt++)
#pragma unroll
        for (int nt = 0; nt < 2; nt++) acc2[mt][nt] = zero;

    const short8* f2base = (const short8*)F2s + wave * 1024 + lane;
#pragma unroll
    for (int ks = 0; ks < 8; ks++) {
        short8 h0 = *(const short8*)&sH[col][ks * 32 + quad * 8];
        short8 h1 = *(const short8*)&sH[16 + col][ks * 32 + quad * 8];
#pragma unroll
        for (int nt = 0; nt < 2; nt++) {
            short8 b = f2base[(nt * 8 + ks) * 64];
            acc2[0][nt] = MFMA16(h0, b, acc2[0][nt]);
            acc2[1][nt] = MFMA16(h1, b, acc2[1][nt]);
        }
    }

#pragma unroll
    for (int nt = 0; nt < 2; nt++) {
        int out = (wave * 2 + nt) * 16 + col;
        float bias = fc2b[out];
#pragma unroll
        for (int mt = 0; mt < 2; mt++)
#pragma unroll
            for (int r = 0; r < 4; r++) {
                int node = node0 + mt * 16 + quad * 4 + r;
                recon[node * 128 + out] = acc2[mt][nt][r] + bias;
            }
    }
}

extern "C" void kernel_launch(void* const* d_in, const int* in_sizes, int n_in,
                              void* d_out, int out_size, void* d_ws, size_t ws_size,
                              hipStream_t stream) {
    const float* x    = (const float*)d_in[0];
    const int*   ei   = (const int*)d_in[1];
    const int E = in_sizes[1] / 2;
    const int* src = ei;
    const int* dst = ei + E;
    const float* Wl1  = (const float*)d_in[2];
    const float* bl1  = (const float*)d_in[3];
    const float* Wr1  = (const float*)d_in[4];
    const float* Wl2  = (const float*)d_in[5];
    const float* bl2  = (const float*)d_in[6];
    const float* Wr2  = (const float*)d_in[7];
    const float* fc1W = (const float*)d_in[8];
    const float* fc1b = (const float*)d_in[9];
    const float* fc2W = (const float*)d_in[10];
    const float* fc2b = (const float*)d_in[11];

    float* out   = (float*)d_out;
    float* emb   = out;                           // N*64
    float* recon = out + (size_t)N_NODES * D_E;   // N*128

    // workspace layout (512-aligned offsets)
    char* ws = (char*)d_ws;
    unsigned short* xbf    = (unsigned short*)(ws);             // 25,600,000 B
    unsigned*       meanbf = (unsigned*)(ws + 25600000);        // 25,600,000 B
    unsigned short* z2bf   = (unsigned short*)(ws + 51200000);  // 12,800,000 B
    unsigned*       embbf  = (unsigned*)(ws + 64000000);        // 12,800,000 B
    int* degI   = (int*)(ws + 76800000);                        //    400,000 B
    int* offs   = (int*)(ws + 77200384);                        //    400,000 B
    int* gcur      = (int*)(ws + 77600768);                     // 196*64 B padded counters
    int* bucketCnt = (int*)(ws + 77617152);                     // 196*64 B padded counters
    int* bucketOffs= (int*)(ws + 77633536);                     // 197*4 B
    int* srcS   = (int*)(ws + 78001664);                        //  6,400,000 B
    unsigned short* W1s = (unsigned short*)(ws + 84401664);     //    131,072 B
    unsigned short* W2s = (unsigned short*)(ws + 84532736);     //     65,536 B
    unsigned short* F1s = (unsigned short*)(ws + 84598272);     //     32,768 B
    unsigned short* F2s = (unsigned short*)(ws + 84631040);     //     65,536 B
    // end 84,696,576 B
    // pairs buffer (6.4MB) reuses the meanbf region: its lifetime ends before
    // gather_mean_bf writes meanbf.
    unsigned* pairs = (unsigned*)(ws + 25600000);

    // gcur + bucketCnt are contiguous: one memset
    hipMemsetAsync(gcur, 0, 32768, stream);

    convert_weights<<<(147456 + 255) / 256, 256, 0, stream>>>(
        Wl1, Wr1, Wl2, Wr2, fc1W, fc2W, W1s, W2s, F1s, F2s);
    convert_x<<<(N_NODES * 32 + 255) / 256, 256, 0, stream>>>(
        (const float4*)x, (uint2*)xbf, N_NODES * 32);

    // counting sort of edges by dst (bucket hist + radix two-pass)
    const int nChunks = (E + CHUNK - 1) / CHUNK;  // 196 at E=1.6M
    bucket_hist<<<nChunks, RCR_T, 0, stream>>>(dst, bucketCnt, E);
    bucket_scan<<<1, 256, 0, stream>>>(bucketCnt, bucketOffs);
    radix_count_reserve<<<nChunks, RCR_T, 0, stream>>>(
        src, dst, bucketOffs, gcur, pairs, E);
    radix_scatter2<<<NBUCK, 512, 0, stream>>>(
        pairs, bucketOffs, degI, offs, srcS);

    // layer 1
    gather_mean_bf<<<(N_NODES + 3) / 4, 256, 0, stream>>>(
        (const uint4*)xbf, srcS, offs, degI, (uint4*)meanbf);
    layer1_mfma<<<N_NODES / MT, 256, 0, stream>>>(
        (const unsigned*)xbf, meanbf, W1s, bl1, W2s, z2bf, emb);

    // layer 2 aggregation + emb finalize
    gather_emb<<<(N_NODES + 3) / 4, 256, 0, stream>>>(
        (const uint4*)z2bf, srcS, offs, degI, bl2, emb, (uint4*)embbf);

    // decoder
    decoder_mfma<<<N_NODES / MT, 256, 0, stream>>>(
        embbf, F1s, fc1b, F2s, fc2b, recon);
}

// Round 11
// 324.189 us; speedup vs baseline: 1.1535x; 1.1535x over previous
//
#include <hip/hip_runtime.h>
#include <hip/hip_bf16.h>

#define N_NODES 100000
#define D_IN 128
#define D_H 256
#define D_E 64
#define MT 32        // nodes per GEMM block
#define BSHIFT 9                                   // 512 nodes per bucket
#define NBUCK ((N_NODES + 511) >> BSHIFT)          // 196
#define CHUNK 8192                                 // edges per pass-1 block
#define RCR_T 1024                                 // pass-1 threads
#define RCR_ILP (CHUNK / RCR_T)                    // 8 edges per thread

typedef __attribute__((ext_vector_type(8))) short short8;
typedef __attribute__((ext_vector_type(4))) float floatx4;

__device__ inline unsigned short f2bf(float f) {
    union { float f; unsigned u; } v; v.f = f;
    unsigned r = v.u + 0x7FFF + ((v.u >> 16) & 1);
    return (unsigned short)(r >> 16);
}
__device__ inline unsigned f2bf2(float a, float b) {
    return (unsigned)f2bf(a) | ((unsigned)f2bf(b) << 16);
}
__device__ inline float2 bf2f2(unsigned v) {
    union { unsigned u; float f; } lo, hi;
    lo.u = v << 16;
    hi.u = v & 0xffff0000u;
    return make_float2(lo.f, hi.f);  // .x = lower-address bf16
}

#define MFMA16(a, b, c) __builtin_amdgcn_mfma_f32_16x16x32_bf16((a), (b), (c), 0, 0, 0)

// ---------------- weight pre-pack to bf16, SWIZZLED to MFMA fragment order ----
__global__ void convert_weights(const float* __restrict__ Wl1, const float* __restrict__ Wr1,
                                const float* __restrict__ Wl2, const float* __restrict__ Wr2,
                                const float* __restrict__ fc1W, const float* __restrict__ fc2W,
                                unsigned short* __restrict__ W1s, unsigned short* __restrict__ W2s,
                                unsigned short* __restrict__ F1s, unsigned short* __restrict__ F2s) {
    int idx = blockIdx.x * blockDim.x + threadIdx.x;
    if (idx < 65536) {
        int out = idx >> 8, k = idx & 255;
        float v = (k < 128) ? Wl1[out * 128 + k] : Wr1[out * 128 + (k - 128)];
        int ks = k >> 5, quad = (k >> 3) & 3, e = k & 7, col = out & 15;
        int g = (out >> 4) * 8 + ks;
        W1s[(g * 64 + quad * 16 + col) * 8 + e] = f2bf(v);
    } else if (idx < 98304) {
        int i = idx - 65536; int out = i >> 8, k = i & 255;
        float v = (out < 64) ? Wl2[out * 256 + k] : Wr2[(out - 64) * 256 + k];
        int ks = k >> 5, quad = (k >> 3) & 3, e = k & 7, col = out & 15;
        int g = (out >> 4) * 8 + ks;
        W2s[(g * 64 + quad * 16 + col) * 8 + e] = f2bf(v);
    } else if (idx < 114688) {
        int i = idx - 98304;
        int out = i >> 6, k = i & 63;
        float v = fc1W[i];
        int ks = k >> 5, quad = (k >> 3) & 3, e = k & 7, col = out & 15;
        int g = (out >> 4) * 2 + ks;
        F1s[(g * 64 + quad * 16 + col) * 8 + e] = f2bf(v);
    } else if (idx < 147456) {
        int i = idx - 114688;
        int out = i >> 8, k = i & 255;
        float v = fc2W[i];
        int ks = k >> 5, quad = (k >> 3) & 3, e = k & 7, col = out & 15;
        int g = (out >> 4) * 8 + ks;
        F2s[(g * 64 + quad * 16 + col) * 8 + e] = f2bf(v);
    }
}

// x fp32 -> bf16 (packed pairs)
__global__ void convert_x(const float4* __restrict__ x4, uint2* __restrict__ xbf2, int total4) {
    int idx = blockIdx.x * blockDim.x + threadIdx.x;
    if (idx >= total4) return;
    float4 v = x4[idx];
    uint2 o;
    o.x = f2bf2(v.x, v.y);
    o.y = f2bf2(v.z, v.w);
    xbf2[idx] = o;
}

// ---------------- bucket-level histogram ----------
__global__ __launch_bounds__(RCR_T) void bucket_hist(
        const int* __restrict__ dst, int* __restrict__ bucketCnt, int E) {
    __shared__ int hist[256];
    const int t = threadIdx.x;
    if (t < 256) hist[t] = 0;
    __syncthreads();
    const int e0 = blockIdx.x * CHUNK;
    if (e0 + CHUNK <= E) {
        int dv[RCR_ILP];
#pragma unroll
        for (int i = 0; i < RCR_ILP; i++) dv[i] = dst[e0 + t + i * RCR_T];
#pragma unroll
        for (int i = 0; i < RCR_ILP; i++) atomicAdd(&hist[dv[i] >> BSHIFT], 1);
    } else {
        for (int e = e0 + t; e < E; e += RCR_T)
            atomicAdd(&hist[dst[e] >> BSHIFT], 1);
    }
    __syncthreads();
    if (t < NBUCK && hist[t] > 0) atomicAdd(&bucketCnt[t * 16], hist[t]);
}

// single-block exclusive scan of 196 bucket counts -> bucketOffs[0..196]
__global__ void bucket_scan(const int* __restrict__ bucketCnt,
                            int* __restrict__ bucketOffs) {
    __shared__ int s[256];
    int t = threadIdx.x;
    int v = (t < NBUCK) ? bucketCnt[t * 16] : 0;
    s[t] = v;
    __syncthreads();
    for (int off = 1; off < 256; off <<= 1) {
        int tv = (t >= off) ? s[t - off] : 0;
        __syncthreads();
        s[t] += tv;
        __syncthreads();
    }
    if (t < NBUCK) bucketOffs[t] = s[t] - v;
    if (t == NBUCK - 1) bucketOffs[NBUCK] = s[t];
}

// ---------------- two-pass radix partition (per-block reservation) ----------
__global__ __launch_bounds__(RCR_T) void radix_count_reserve(
        const int* __restrict__ src, const int* __restrict__ dst,
        const int* __restrict__ bucketOffs, int* __restrict__ gcur,
        unsigned* __restrict__ pairs, int E) {
    __shared__ int hist[256];
    __shared__ int sBase[256];
    __shared__ int sCur[256];
    const int t = threadIdx.x;
    if (t < 256) { hist[t] = 0; sCur[t] = 0; }
    __syncthreads();
    const int e0 = blockIdx.x * CHUNK;

    if (e0 + CHUNK <= E) {
        int dv[RCR_ILP], sv[RCR_ILP];
#pragma unroll
        for (int i = 0; i < RCR_ILP; i++) dv[i] = dst[e0 + t + i * RCR_T];
#pragma unroll
        for (int i = 0; i < RCR_ILP; i++) atomicAdd(&hist[dv[i] >> BSHIFT], 1);
        __syncthreads();
        if (t < NBUCK && hist[t] > 0)
            sBase[t] = bucketOffs[t] + atomicAdd(&gcur[t * 16], hist[t]);
        __syncthreads();
#pragma unroll
        for (int i = 0; i < RCR_ILP; i++) sv[i] = src[e0 + t + i * RCR_T];
#pragma unroll
        for (int i = 0; i < RCR_ILP; i++) {
            int d = dv[i];
            int b = d >> BSHIFT;
            int pos = sBase[b] + atomicAdd(&sCur[b], 1);
            pairs[pos] = (unsigned)sv[i] | ((unsigned)(d & 511) << 20);
        }
    } else {
        const int e1 = E;
        for (int e = e0 + t; e < e1; e += RCR_T)
            atomicAdd(&hist[dst[e] >> BSHIFT], 1);
        __syncthreads();
        if (t < NBUCK && hist[t] > 0)
            sBase[t] = bucketOffs[t] + atomicAdd(&gcur[t * 16], hist[t]);
        __syncthreads();
        for (int e = e0 + t; e < e1; e += RCR_T) {
            int d = dst[e];
            int b = d >> BSHIFT;
            int pos = sBase[b] + atomicAdd(&sCur[b], 1);
            pairs[pos] = (unsigned)src[e] | ((unsigned)(d & 511) << 20);
        }
    }
}

// Pass 2: one WG per bucket. LDS-histogram the 512 local dst's, LDS scan ->
// write degI/offs directly, then scatter into the bucket's srcS window.
__global__ __launch_bounds__(512) void radix_scatter2(
        const unsigned* __restrict__ pairs, const int* __restrict__ bucketOffs,
        int* __restrict__ degI, int* __restrict__ offs,
        int* __restrict__ srcS) {
    __shared__ int sCnt[512];
    __shared__ int sOff[512];
    const int b = blockIdx.x;
    const int lo = b << BSHIFT;
    const int t = threadIdx.x;
    sCnt[t] = 0;
    __syncthreads();
    const int start = bucketOffs[b];
    const int end = bucketOffs[b + 1];
    for (int i = start + t; i < end; i += 512)
        atomicAdd(&sCnt[pairs[i] >> 20], 1);
    __syncthreads();
    int v = sCnt[t];
    sOff[t] = v;
    __syncthreads();
    for (int off = 1; off < 512; off <<= 1) {
        int tv = (t >= off) ? sOff[t - off] : 0;
        __syncthreads();
        sOff[t] += tv;
        __syncthreads();
    }
    int excl = sOff[t] - v;
    int node = lo + t;
    if (node < N_NODES) {
        degI[node] = v;
        offs[node] = start + excl;
    }
    __syncthreads();
    sCnt[t] = start + excl;
    __syncthreads();
    int i = start + t;
    for (; i + 3 * 512 < end; i += 4 * 512) {
        unsigned p0 = pairs[i];
        unsigned p1 = pairs[i + 512];
        unsigned p2 = pairs[i + 1024];
        unsigned p3 = pairs[i + 1536];
        int dl0 = (int)(p0 >> 20), dl1 = (int)(p1 >> 20);
        int dl2 = (int)(p2 >> 20), dl3 = (int)(p3 >> 20);
        int q0 = atomicAdd(&sCnt[dl0], 1);
        int q1 = atomicAdd(&sCnt[dl1], 1);
        int q2 = atomicAdd(&sCnt[dl2], 1);
        int q3 = atomicAdd(&sCnt[dl3], 1);
        srcS[q0] = (int)(p0 & 0xFFFFFu);
        srcS[q1] = (int)(p1 & 0xFFFFFu);
        srcS[q2] = (int)(p2 & 0xFFFFFu);
        srcS[q3] = (int)(p3 & 0xFFFFFu);
    }
    for (; i < end; i += 512) {
        unsigned p = pairs[i];
        int dl = (int)(p >> 20);
        int pos = atomicAdd(&sCnt[dl], 1);
        srcS[pos] = (int)(p & 0xFFFFFu);
    }
}

// ---------------- gather: mean of bf16 x rows -> packed bf16 mean ------------
// ONE QUARTER-WAVE PER NODE: 16 lanes x uint4 = 256B row; 4 independent nodes
// per wave; 8-deep edge unroll -> 8 row-loads in flight at typical cnt=16.
// No cross-lane reduction (each quarter owns its node).
#define ACC8(v)                                                   \
    { float2 f_;                                                  \
      f_ = bf2f2((v).x); s0 += f_.x; s1 += f_.y;                  \
      f_ = bf2f2((v).y); s2 += f_.x; s3 += f_.y;                  \
      f_ = bf2f2((v).z); s4 += f_.x; s5 += f_.y;                  \
      f_ = bf2f2((v).w); s6 += f_.x; s7 += f_.y; }

__global__ __launch_bounds__(256) void gather_mean_bf(
        const uint4* __restrict__ xb4, const int* __restrict__ srcS,
        const int* __restrict__ offs, const int* __restrict__ degI,
        uint4* __restrict__ mean4) {
    const int wave = threadIdx.x >> 6, lane = threadIdx.x & 63;
    const int q = lane >> 4, l16 = lane & 15;
    const int n = (blockIdx.x * 4 + wave) * 4 + q;
    if (n >= N_NODES) return;
    const int start = offs[n], cnt = degI[n];
    const int* sp = srcS + start;
    float s0 = 0.f, s1 = 0.f, s2 = 0.f, s3 = 0.f;
    float s4 = 0.f, s5 = 0.f, s6 = 0.f, s7 = 0.f;
    int j = 0;
    for (; j + 8 <= cnt; j += 8) {
        int i0 = sp[j],     i1 = sp[j + 1], i2 = sp[j + 2], i3 = sp[j + 3];
        int i4 = sp[j + 4], i5 = sp[j + 5], i6 = sp[j + 6], i7 = sp[j + 7];
        uint4 v0 = xb4[i0 * 16 + l16];
        uint4 v1 = xb4[i1 * 16 + l16];
        uint4 v2 = xb4[i2 * 16 + l16];
        uint4 v3 = xb4[i3 * 16 + l16];
        uint4 v4 = xb4[i4 * 16 + l16];
        uint4 v5 = xb4[i5 * 16 + l16];
        uint4 v6 = xb4[i6 * 16 + l16];
        uint4 v7 = xb4[i7 * 16 + l16];
        ACC8(v0); ACC8(v1); ACC8(v2); ACC8(v3);
        ACC8(v4); ACC8(v5); ACC8(v6); ACC8(v7);
    }
    for (; j + 4 <= cnt; j += 4) {
        int i0 = sp[j], i1 = sp[j + 1], i2 = sp[j + 2], i3 = sp[j + 3];
        uint4 v0 = xb4[i0 * 16 + l16];
        uint4 v1 = xb4[i1 * 16 + l16];
        uint4 v2 = xb4[i2 * 16 + l16];
        uint4 v3 = xb4[i3 * 16 + l16];
        ACC8(v0); ACC8(v1); ACC8(v2); ACC8(v3);
    }
    for (; j < cnt; j++) {
        uint4 v = xb4[sp[j] * 16 + l16];
        ACC8(v);
    }
    float rd = 1.0f / fmaxf((float)cnt, 1.0f);
    uint4 o;
    o.x = f2bf2(s0 * rd, s1 * rd);
    o.y = f2bf2(s2 * rd, s3 * rd);
    o.z = f2bf2(s4 * rd, s5 * rd);
    o.w = f2bf2(s6 * rd, s7 * rd);
    mean4[n * 16 + l16] = o;
}

// ---------------- layer1 MFMA: [mean|x] -> h -> [z2|r2] ----------------
__global__ __launch_bounds__(256, 4) void layer1_mfma(
        const unsigned* __restrict__ xbfu, const unsigned* __restrict__ meanbf,
        const unsigned short* __restrict__ W1s, const float* __restrict__ bl1,
        const unsigned short* __restrict__ W2s,
        unsigned short* __restrict__ z2bf, float* __restrict__ embOut) {
    __shared__ unsigned short sA[MT][264];
    __shared__ unsigned short sH[MT][264];
    const int tid = threadIdx.x;
    const int node0 = blockIdx.x * MT;

    const uint4* mean4 = (const uint4*)meanbf;
    const uint4* x4    = (const uint4*)xbfu;
#pragma unroll
    for (int it = 0; it < 4; it++) {
        int c = tid + it * 256;
        int row = c >> 5, half = (c >> 4) & 1, ci = c & 15;
        uint4 v = half ? x4[(node0 + row) * 16 + ci]
                       : mean4[(node0 + row) * 16 + ci];
        *(uint4*)&sA[row][half * 128 + ci * 8] = v;
    }
    __syncthreads();

    const int wave = tid >> 6, lane = tid & 63;
    const int col = lane & 15, quad = lane >> 4;

    // ---- phase A: h = relu(A @ W1^T + bl1), N=256, K=256 ----
    floatx4 acc[2][4];
    const floatx4 zero = {0.f, 0.f, 0.f, 0.f};
#pragma unroll
    for (int mt = 0; mt < 2; mt++)
#pragma unroll
        for (int nt = 0; nt < 4; nt++) acc[mt][nt] = zero;

    const short8* w1base = (const short8*)W1s + wave * 2048 + lane;
#pragma unroll
    for (int ks = 0; ks < 8; ks++) {
        short8 a0 = *(const short8*)&sA[col][ks * 32 + quad * 8];
        short8 a1 = *(const short8*)&sA[16 + col][ks * 32 + quad * 8];
#pragma unroll
        for (int nt = 0; nt < 4; nt++) {
            short8 b = w1base[(nt * 8 + ks) * 64];
            acc[0][nt] = MFMA16(a0, b, acc[0][nt]);
            acc[1][nt] = MFMA16(a1, b, acc[1][nt]);
        }
    }

#pragma unroll
    for (int nt = 0; nt < 4; nt++) {
        int out = (wave * 4 + nt) * 16 + col;
        float bias = bl1[out];
#pragma unroll
        for (int mt = 0; mt < 2; mt++)
#pragma unroll
            for (int r = 0; r < 4; r++)
                sH[mt * 16 + quad * 4 + r][out] = f2bf(fmaxf(acc[mt][nt][r] + bias, 0.f));
    }
    __syncthreads();

    // ---- phase B: [z2|r2] = h @ W2^T, N=128, K=256 ----
    floatx4 acc2[2][2];
#pragma unroll
    for (int mt = 0; mt < 2; mt++)
#pragma unroll
        for (int nt = 0; nt < 2; nt++) acc2[mt][nt] = zero;

    const short8* w2base = (const short8*)W2s + wave * 1024 + lane;
#pragma unroll
    for (int ks = 0; ks < 8; ks++) {
        short8 h0 = *(const short8*)&sH[col][ks * 32 + quad * 8];
        short8 h1 = *(const short8*)&sH[16 + col][ks * 32 + quad * 8];
#pragma unroll
        for (int nt = 0; nt < 2; nt++) {
            short8 b = w2base[(nt * 8 + ks) * 64];
            acc2[0][nt] = MFMA16(h0, b, acc2[0][nt]);
            acc2[1][nt] = MFMA16(h1, b, acc2[1][nt]);
        }
    }

#pragma unroll
    for (int nt = 0; nt < 2; nt++) {
        int out = (wave * 2 + nt) * 16 + col;
#pragma unroll
        for (int mt = 0; mt < 2; mt++)
#pragma unroll
            for (int r = 0; r < 4; r++) {
                int node = node0 + mt * 16 + quad * 4 + r;
                float v = acc2[mt][nt][r];
                if (out < 64) z2bf[node * 64 + out] = f2bf(v);
                else          embOut[node * 64 + (out - 64)] = v;
            }
    }
}

// ---------------- gather: emb = agg(z2)/deg + bl2 + r2 ----------------
// ONE EIGHTH-WAVE PER NODE: 8 lanes x uint4 = 128B row; 8 nodes/wave;
// 8-deep edge unroll; no cross-lane reduction.
__global__ __launch_bounds__(256) void gather_emb(
        const uint4* __restrict__ z4, const int* __restrict__ srcS,
        const int* __restrict__ offs, const int* __restrict__ degI,
        const float* __restrict__ bl2, float* __restrict__ emb,
        uint4* __restrict__ emb4) {
    const int wave = threadIdx.x >> 6, lane = threadIdx.x & 63;
    const int g = lane >> 3, l8 = lane & 7;
    const int n = (blockIdx.x * 4 + wave) * 8 + g;
    if (n >= N_NODES) return;
    const int start = offs[n], cnt = degI[n];
    const int* sp = srcS + start;
    float s0 = 0.f, s1 = 0.f, s2 = 0.f, s3 = 0.f;
    float s4 = 0.f, s5 = 0.f, s6 = 0.f, s7 = 0.f;
    int j = 0;
    for (; j + 8 <= cnt; j += 8) {
        int i0 = sp[j],     i1 = sp[j + 1], i2 = sp[j + 2], i3 = sp[j + 3];
        int i4 = sp[j + 4], i5 = sp[j + 5], i6 = sp[j + 6], i7 = sp[j + 7];
        uint4 v0 = z4[i0 * 8 + l8];
        uint4 v1 = z4[i1 * 8 + l8];
        uint4 v2 = z4[i2 * 8 + l8];
        uint4 v3 = z4[i3 * 8 + l8];
        uint4 v4 = z4[i4 * 8 + l8];
        uint4 v5 = z4[i5 * 8 + l8];
        uint4 v6 = z4[i6 * 8 + l8];
        uint4 v7 = z4[i7 * 8 + l8];
        ACC8(v0); ACC8(v1); ACC8(v2); ACC8(v3);
        ACC8(v4); ACC8(v5); ACC8(v6); ACC8(v7);
    }
    for (; j + 4 <= cnt; j += 4) {
        int i0 = sp[j], i1 = sp[j + 1], i2 = sp[j + 2], i3 = sp[j + 3];
        uint4 v0 = z4[i0 * 8 + l8];
        uint4 v1 = z4[i1 * 8 + l8];
        uint4 v2 = z4[i2 * 8 + l8];
        uint4 v3 = z4[i3 * 8 + l8];
        ACC8(v0); ACC8(v1); ACC8(v2); ACC8(v3);
    }
    for (; j < cnt; j++) {
        uint4 v = z4[sp[j] * 8 + l8];
        ACC8(v);
    }
    float rd = 1.0f / fmaxf((float)cnt, 1.0f);
    float4 ra = *(const float4*)&emb[n * 64 + l8 * 8];
    float4 rb = *(const float4*)&emb[n * 64 + l8 * 8 + 4];
    float4 ba = *(const float4*)&bl2[l8 * 8];
    float4 bb = *(const float4*)&bl2[l8 * 8 + 4];
    float e0 = s0 * rd + ba.x + ra.x;
    float e1 = s1 * rd + ba.y + ra.y;
    float e2 = s2 * rd + ba.z + ra.z;
    float e3 = s3 * rd + ba.w + ra.w;
    float e4 = s4 * rd + bb.x + rb.x;
    float e5 = s5 * rd + bb.y + rb.y;
    float e6 = s6 * rd + bb.z + rb.z;
    float e7 = s7 * rd + bb.w + rb.w;
    float4 wa = {e0, e1, e2, e3};
    float4 wb = {e4, e5, e6, e7};
    *(float4*)&emb[n * 64 + l8 * 8] = wa;
    *(float4*)&emb[n * 64 + l8 * 8 + 4] = wb;
    uint4 o;
    o.x = f2bf2(e0, e1);
    o.y = f2bf2(e2, e3);
    o.z = f2bf2(e4, e5);
    o.w = f2bf2(e6, e7);
    emb4[n * 8 + l8] = o;
}

// ---------------- decoder MFMA: emb -> hid -> recon ----------------
__global__ __launch_bounds__(256, 4) void decoder_mfma(
        const unsigned* __restrict__ embbf,
        const unsigned short* __restrict__ F1s, const float* __restrict__ fc1b,
        const unsigned short* __restrict__ F2s, const float* __restrict__ fc2b,
        float* __restrict__ recon) {
    __shared__ unsigned short sE[MT][72];
    __shared__ unsigned short sH[MT][264];
    const int tid = threadIdx.x;
    const int node0 = blockIdx.x * MT;

    {
        const uint4* e4 = (const uint4*)embbf;
        int row = tid >> 3, ci = tid & 7;
        *(uint4*)&sE[row][ci * 8] = e4[(node0 + row) * 8 + ci];
    }
    __syncthreads();

    const int wave = tid >> 6, lane = tid & 63;
    const int col = lane & 15, quad = lane >> 4;

    // ---- phase A: hid = relu(emb @ fc1^T + fc1b), N=256, K=64 ----
    floatx4 acc[2][4];
    const floatx4 zero = {0.f, 0.f, 0.f, 0.f};
#pragma unroll
    for (int mt = 0; mt < 2; mt++)
#pragma unroll
        for (int nt = 0; nt < 4; nt++) acc[mt][nt] = zero;

    const short8* f1base = (const short8*)F1s + wave * 512 + lane;
#pragma unroll
    for (int ks = 0; ks < 2; ks++) {
        short8 a0 = *(const short8*)&sE[col][ks * 32 + quad * 8];
        short8 a1 = *(const short8*)&sE[16 + col][ks * 32 + quad * 8];
#pragma unroll
        for (int nt = 0; nt < 4; nt++) {
            short8 b = f1base[(nt * 2 + ks) * 64];
            acc[0][nt] = MFMA16(a0, b, acc[0][nt]);
            acc[1][nt] = MFMA16(a1, b, acc[1][nt]);
        }
    }

#pragma unroll
    for (int nt = 0; nt < 4; nt++) {
        int out = (wave * 4 + nt) * 16 + col;
        float bias = fc1b[out];
#pragma unroll
        for (int mt = 0; mt < 2; mt++)
#pragma unroll
            for (int r = 0; r < 4; r++)
                sH[mt * 16 + quad * 4 + r][out] = f2bf(fmaxf(acc[mt][nt][r] + bias, 0.f));
    }
    __syncthreads();

    // ---- phase B: recon = hid @ fc2^T + fc2b, N=128, K=256 ----
    floatx4 acc2[2][2];
#pragma unroll
    for (int mt = 0; mt < 2; mt++)
#pragma unroll
        for (int nt = 0; nt < 2; nt++) acc2[mt][nt] = zero;

    const short8* f2base = (const short8*)F2s + wave * 1024 + lane;
#pragma unroll
    for (int ks = 0; ks < 8; ks++) {
        short8 h0 = *(const short8*)&sH[col][ks * 32 + quad * 8];
        short8 h1 = *(const short8*)&sH[16 + col][ks * 32 + quad * 8];
#pragma unroll
        for (int nt = 0; nt < 2; nt++) {
            short8 b = f2base[(nt * 8 + ks) * 64];
            acc2[0][nt] = MFMA16(h0, b, acc2[0][nt]);
            acc2[1][nt] = MFMA16(h1, b, acc2[1][nt]);
        }
    }

#pragma unroll
    for (int nt = 0; nt < 2; nt++) {
        int out = (wave * 2 + nt) * 16 + col;
        float bias = fc2b[out];
#pragma unroll
        for (int mt = 0; mt < 2; mt++)
#pragma unroll
            for (int r = 0; r < 4; r++) {
                int node = node0 + mt * 16 + quad * 4 + r;
                recon[node * 128 + out] = acc2[mt][nt][r] + bias;
            }
    }
}

extern "C" void kernel_launch(void* const* d_in, const int* in_sizes, int n_in,
                              void* d_out, int out_size, void* d_ws, size_t ws_size,
                              hipStream_t stream) {
    const float* x    = (const float*)d_in[0];
    const int*   ei   = (const int*)d_in[1];
    const int E = in_sizes[1] / 2;
    const int* src = ei;
    const int* dst = ei + E;
    const float* Wl1  = (const float*)d_in[2];
    const float* bl1  = (const float*)d_in[3];
    const float* Wr1  = (const float*)d_in[4];
    const float* Wl2  = (const float*)d_in[5];
    const float* bl2  = (const float*)d_in[6];
    const float* Wr2  = (const float*)d_in[7];
    const float* fc1W = (const float*)d_in[8];
    const float* fc1b = (const float*)d_in[9];
    const float* fc2W = (const float*)d_in[10];
    const float* fc2b = (const float*)d_in[11];

    float* out   = (float*)d_out;
    float* emb   = out;                           // N*64
    float* recon = out + (size_t)N_NODES * D_E;   // N*128

    // workspace layout (512-aligned offsets)
    char* ws = (char*)d_ws;
    unsigned short* xbf    = (unsigned short*)(ws);             // 25,600,000 B
    unsigned*       meanbf = (unsigned*)(ws + 25600000);        // 25,600,000 B
    unsigned short* z2bf   = (unsigned short*)(ws + 51200000);  // 12,800,000 B
    unsigned*       embbf  = (unsigned*)(ws + 64000000);        // 12,800,000 B
    int* degI   = (int*)(ws + 76800000);                        //    400,000 B
    int* offs   = (int*)(ws + 77200384);                        //    400,000 B
    int* gcur      = (int*)(ws + 77600768);                     // 196*64 B padded counters
    int* bucketCnt = (int*)(ws + 77617152);                     // 196*64 B padded counters
    int* bucketOffs= (int*)(ws + 77633536);                     // 197*4 B
    int* srcS   = (int*)(ws + 78001664);                        //  6,400,000 B
    unsigned short* W1s = (unsigned short*)(ws + 84401664);     //    131,072 B
    unsigned short* W2s = (unsigned short*)(ws + 84532736);     //     65,536 B
    unsigned short* F1s = (unsigned short*)(ws + 84598272);     //     32,768 B
    unsigned short* F2s = (unsigned short*)(ws + 84631040);     //     65,536 B
    // end 84,696,576 B
    // pairs buffer (6.4MB) reuses the meanbf region: its lifetime ends before
    // gather_mean_bf writes meanbf.
    unsigned* pairs = (unsigned*)(ws + 25600000);

    // gcur + bucketCnt are contiguous: one memset
    hipMemsetAsync(gcur, 0, 32768, stream);

    convert_weights<<<(147456 + 255) / 256, 256, 0, stream>>>(
        Wl1, Wr1, Wl2, Wr2, fc1W, fc2W, W1s, W2s, F1s, F2s);
    convert_x<<<(N_NODES * 32 + 255) / 256, 256, 0, stream>>>(
        (const float4*)x, (uint2*)xbf, N_NODES * 32);

    // counting sort of edges by dst (bucket hist + radix two-pass)
    const int nChunks = (E + CHUNK - 1) / CHUNK;  // 196 at E=1.6M
    bucket_hist<<<nChunks, RCR_T, 0, stream>>>(dst, bucketCnt, E);
    bucket_scan<<<1, 256, 0, stream>>>(bucketCnt, bucketOffs);
    radix_count_reserve<<<nChunks, RCR_T, 0, stream>>>(
        src, dst, bucketOffs, gcur, pairs, E);
    radix_scatter2<<<NBUCK, 512, 0, stream>>>(
        pairs, bucketOffs, degI, offs, srcS);

    // layer 1 (gather: 16 nodes per 256-thread block)
    gather_mean_bf<<<(N_NODES + 15) / 16, 256, 0, stream>>>(
        (const uint4*)xbf, srcS, offs, degI, (uint4*)meanbf);
    layer1_mfma<<<N_NODES / MT, 256, 0, stream>>>(
        (const unsigned*)xbf, meanbf, W1s, bl1, W2s, z2bf, emb);

    // layer 2 aggregation + emb finalize (32 nodes per block)
    gather_emb<<<(N_NODES + 31) / 32, 256, 0, stream>>>(
        (const uint4*)z2bf, srcS, offs, degI, bl2, emb, (uint4*)embbf);

    // decoder
    decoder_mfma<<<N_NODES / MT, 256, 0, stream>>>(
        embbf, F1s, fc1b, F2s, fc2b, recon);
}

// Round 12
// 315.456 us; speedup vs baseline: 1.1854x; 1.0277x over previous
//
#include <hip/hip_runtime.h>
#include <hip/hip_bf16.h>

#define N_NODES 100000
#define D_IN 128
#define D_H 256
#define D_E 64
#define MT 32        // nodes per GEMM block
#define BSHIFT 9                                   // 512 nodes per bucket
#define NBUCK ((N_NODES + 511) >> BSHIFT)          // 196
#define CHUNK 8192                                 // edges per pass-1 block
#define RCR_T 1024                                 // pass-1 threads
#define RCR_ILP (CHUNK / RCR_T)                    // 8 edges per thread

typedef __attribute__((ext_vector_type(8))) short short8;
typedef __attribute__((ext_vector_type(4))) float floatx4;

__device__ inline unsigned short f2bf(float f) {
    union { float f; unsigned u; } v; v.f = f;
    unsigned r = v.u + 0x7FFF + ((v.u >> 16) & 1);
    return (unsigned short)(r >> 16);
}
__device__ inline unsigned f2bf2(float a, float b) {
    return (unsigned)f2bf(a) | ((unsigned)f2bf(b) << 16);
}
__device__ inline float2 bf2f2(unsigned v) {
    union { unsigned u; float f; } lo, hi;
    lo.u = v << 16;
    hi.u = v & 0xffff0000u;
    return make_float2(lo.f, hi.f);  // .x = lower-address bf16
}

#define MFMA16(a, b, c) __builtin_amdgcn_mfma_f32_16x16x32_bf16((a), (b), (c), 0, 0, 0)

// ---------------- weight pre-pack to bf16, SWIZZLED to MFMA fragment order ----
__global__ void convert_weights(const float* __restrict__ Wl1, const float* __restrict__ Wr1,
                                const float* __restrict__ Wl2, const float* __restrict__ Wr2,
                                const float* __restrict__ fc1W, const float* __restrict__ fc2W,
                                unsigned short* __restrict__ W1s, unsigned short* __restrict__ W2s,
                                unsigned short* __restrict__ F1s, unsigned short* __restrict__ F2s) {
    int idx = blockIdx.x * blockDim.x + threadIdx.x;
    if (idx < 65536) {
        int out = idx >> 8, k = idx & 255;
        float v = (k < 128) ? Wl1[out * 128 + k] : Wr1[out * 128 + (k - 128)];
        int ks = k >> 5, quad = (k >> 3) & 3, e = k & 7, col = out & 15;
        int g = (out >> 4) * 8 + ks;
        W1s[(g * 64 + quad * 16 + col) * 8 + e] = f2bf(v);
    } else if (idx < 98304) {
        int i = idx - 65536; int out = i >> 8, k = i & 255;
        float v = (out < 64) ? Wl2[out * 256 + k] : Wr2[(out - 64) * 256 + k];
        int ks = k >> 5, quad = (k >> 3) & 3, e = k & 7, col = out & 15;
        int g = (out >> 4) * 8 + ks;
        W2s[(g * 64 + quad * 16 + col) * 8 + e] = f2bf(v);
    } else if (idx < 114688) {
        int i = idx - 98304;
        int out = i >> 6, k = i & 63;
        float v = fc1W[i];
        int ks = k >> 5, quad = (k >> 3) & 3, e = k & 7, col = out & 15;
        int g = (out >> 4) * 2 + ks;
        F1s[(g * 64 + quad * 16 + col) * 8 + e] = f2bf(v);
    } else if (idx < 147456) {
        int i = idx - 114688;
        int out = i >> 8, k = i & 255;
        float v = fc2W[i];
        int ks = k >> 5, quad = (k >> 3) & 3, e = k & 7, col = out & 15;
        int g = (out >> 4) * 8 + ks;
        F2s[(g * 64 + quad * 16 + col) * 8 + e] = f2bf(v);
    }
}

// x fp32 -> bf16 (packed pairs)
__global__ void convert_x(const float4* __restrict__ x4, uint2* __restrict__ xbf2, int total4) {
    int idx = blockIdx.x * blockDim.x + threadIdx.x;
    if (idx >= total4) return;
    float4 v = x4[idx];
    uint2 o;
    o.x = f2bf2(v.x, v.y);
    o.y = f2bf2(v.z, v.w);
    xbf2[idx] = o;
}

// ---------------- bucket-level histogram ----------
__global__ __launch_bounds__(RCR_T) void bucket_hist(
        const int* __restrict__ dst, int* __restrict__ bucketCnt, int E) {
    __shared__ int hist[256];
    const int t = threadIdx.x;
    if (t < 256) hist[t] = 0;
    __syncthreads();
    const int e0 = blockIdx.x * CHUNK;
    if (e0 + CHUNK <= E) {
        int dv[RCR_ILP];
#pragma unroll
        for (int i = 0; i < RCR_ILP; i++) dv[i] = dst[e0 + t + i * RCR_T];
#pragma unroll
        for (int i = 0; i < RCR_ILP; i++) atomicAdd(&hist[dv[i] >> BSHIFT], 1);
    } else {
        for (int e = e0 + t; e < E; e += RCR_T)
            atomicAdd(&hist[dst[e] >> BSHIFT], 1);
    }
    __syncthreads();
    if (t < NBUCK && hist[t] > 0) atomicAdd(&bucketCnt[t * 16], hist[t]);
}

// single-block exclusive scan of 196 bucket counts -> bucketOffs[0..196]
__global__ void bucket_scan(const int* __restrict__ bucketCnt,
                            int* __restrict__ bucketOffs) {
    __shared__ int s[256];
    int t = threadIdx.x;
    int v = (t < NBUCK) ? bucketCnt[t * 16] : 0;
    s[t] = v;
    __syncthreads();
    for (int off = 1; off < 256; off <<= 1) {
        int tv = (t >= off) ? s[t - off] : 0;
        __syncthreads();
        s[t] += tv;
        __syncthreads();
    }
    if (t < NBUCK) bucketOffs[t] = s[t] - v;
    if (t == NBUCK - 1) bucketOffs[NBUCK] = s[t];
}

// ---------------- two-pass radix partition (per-block reservation) ----------
__global__ __launch_bounds__(RCR_T) void radix_count_reserve(
        const int* __restrict__ src, const int* __restrict__ dst,
        const int* __restrict__ bucketOffs, int* __restrict__ gcur,
        unsigned* __restrict__ pairs, int E) {
    __shared__ int hist[256];
    __shared__ int sBase[256];
    __shared__ int sCur[256];
    const int t = threadIdx.x;
    if (t < 256) { hist[t] = 0; sCur[t] = 0; }
    __syncthreads();
    const int e0 = blockIdx.x * CHUNK;

    if (e0 + CHUNK <= E) {
        int dv[RCR_ILP], sv[RCR_ILP];
#pragma unroll
        for (int i = 0; i < RCR_ILP; i++) dv[i] = dst[e0 + t + i * RCR_T];
#pragma unroll
        for (int i = 0; i < RCR_ILP; i++) atomicAdd(&hist[dv[i] >> BSHIFT], 1);
        __syncthreads();
        if (t < NBUCK && hist[t] > 0)
            sBase[t] = bucketOffs[t] + atomicAdd(&gcur[t * 16], hist[t]);
        __syncthreads();
#pragma unroll
        for (int i = 0; i < RCR_ILP; i++) sv[i] = src[e0 + t + i * RCR_T];
#pragma unroll
        for (int i = 0; i < RCR_ILP; i++) {
            int d = dv[i];
            int b = d >> BSHIFT;
            int pos = sBase[b] + atomicAdd(&sCur[b], 1);
            pairs[pos] = (unsigned)sv[i] | ((unsigned)(d & 511) << 20);
        }
    } else {
        const int e1 = E;
        for (int e = e0 + t; e < e1; e += RCR_T)
            atomicAdd(&hist[dst[e] >> BSHIFT], 1);
        __syncthreads();
        if (t < NBUCK && hist[t] > 0)
            sBase[t] = bucketOffs[t] + atomicAdd(&gcur[t * 16], hist[t]);
        __syncthreads();
        for (int e = e0 + t; e < e1; e += RCR_T) {
            int d = dst[e];
            int b = d >> BSHIFT;
            int pos = sBase[b] + atomicAdd(&sCur[b], 1);
            pairs[pos] = (unsigned)src[e] | ((unsigned)(d & 511) << 20);
        }
    }
}

// Pass 2: one WG per bucket. LDS-histogram the 512 local dst's, LDS scan ->
// write degI/offs directly, then scatter into the bucket's srcS window.
__global__ __launch_bounds__(512) void radix_scatter2(
        const unsigned* __restrict__ pairs, const int* __restrict__ bucketOffs,
        int* __restrict__ degI, int* __restrict__ offs,
        int* __restrict__ srcS) {
    __shared__ int sCnt[512];
    __shared__ int sOff[512];
    const int b = blockIdx.x;
    const int lo = b << BSHIFT;
    const int t = threadIdx.x;
    sCnt[t] = 0;
    __syncthreads();
    const int start = bucketOffs[b];
    const int end = bucketOffs[b + 1];
    for (int i = start + t; i < end; i += 512)
        atomicAdd(&sCnt[pairs[i] >> 20], 1);
    __syncthreads();
    int v = sCnt[t];
    sOff[t] = v;
    __syncthreads();
    for (int off = 1; off < 512; off <<= 1) {
        int tv = (t >= off) ? sOff[t - off] : 0;
        __syncthreads();
        sOff[t] += tv;
        __syncthreads();
    }
    int excl = sOff[t] - v;
    int node = lo + t;
    if (node < N_NODES) {
        degI[node] = v;
        offs[node] = start + excl;
    }
    __syncthreads();
    sCnt[t] = start + excl;
    __syncthreads();
    int i = start + t;
    for (; i + 3 * 512 < end; i += 4 * 512) {
        unsigned p0 = pairs[i];
        unsigned p1 = pairs[i + 512];
        unsigned p2 = pairs[i + 1024];
        unsigned p3 = pairs[i + 1536];
        int dl0 = (int)(p0 >> 20), dl1 = (int)(p1 >> 20);
        int dl2 = (int)(p2 >> 20), dl3 = (int)(p3 >> 20);
        int q0 = atomicAdd(&sCnt[dl0], 1);
        int q1 = atomicAdd(&sCnt[dl1], 1);
        int q2 = atomicAdd(&sCnt[dl2], 1);
        int q3 = atomicAdd(&sCnt[dl3], 1);
        srcS[q0] = (int)(p0 & 0xFFFFFu);
        srcS[q1] = (int)(p1 & 0xFFFFFu);
        srcS[q2] = (int)(p2 & 0xFFFFFu);
        srcS[q3] = (int)(p3 & 0xFFFFFu);
    }
    for (; i < end; i += 512) {
        unsigned p = pairs[i];
        int dl = (int)(p >> 20);
        int pos = atomicAdd(&sCnt[dl], 1);
        srcS[pos] = (int)(p & 0xFFFFFu);
    }
}

#define ACC8(v)                                                   \
    { float2 f_;                                                  \
      f_ = bf2f2((v).x); s0 += f_.x; s1 += f_.y;                  \
      f_ = bf2f2((v).y); s2 += f_.x; s3 += f_.y;                  \
      f_ = bf2f2((v).z); s4 += f_.x; s5 += f_.y;                  \
      f_ = bf2f2((v).w); s6 += f_.x; s7 += f_.y; }

// ---------------- FUSED layer1: gather mean (quarter-wave/node) + MFMA ------
// Phase 0: stage x rows into sA[:,128:256]; gather means into sA[:,0:128]
//          (quarter-wave = 16 lanes x uint4 = 256B row; 2 nodes per quarter;
//           8-deep edge unroll). Eliminates the meanbf round trip (50 MB).
// Phase A/B: identical MFMA pipeline as before.
__global__ __launch_bounds__(256, 4) void fused_layer1(
        const uint4* __restrict__ xb4, const int* __restrict__ srcS,
        const int* __restrict__ offs, const int* __restrict__ degI,
        const unsigned short* __restrict__ W1s, const float* __restrict__ bl1,
        const unsigned short* __restrict__ W2s,
        unsigned short* __restrict__ z2bf, float* __restrict__ embOut) {
    __shared__ unsigned short sA[MT][264];
    __shared__ unsigned short sH[MT][264];
    const int tid = threadIdx.x;
    const int node0 = blockIdx.x * MT;
    const int wave = tid >> 6, lane = tid & 63;
    const int q = lane >> 4, l16 = lane & 15;

    // x staging: cols 128..255 (512 x 16B chunks)
#pragma unroll
    for (int it = 0; it < 2; it++) {
        int c = tid + it * 256;
        int row = c >> 4, ci = c & 15;
        *(uint4*)&sA[row][128 + ci * 8] = xb4[(node0 + row) * 16 + ci];
    }

    // gather means: quarter qid handles nodes node0 + qid*2 {+0,+1}
    const int qid = wave * 4 + q;  // 0..15
#pragma unroll
    for (int half = 0; half < 2; half++) {
        const int nl = qid * 2 + half;
        const int n = node0 + nl;
        const int start = offs[n], cnt = degI[n];
        const int* sp = srcS + start;
        float s0 = 0.f, s1 = 0.f, s2 = 0.f, s3 = 0.f;
        float s4 = 0.f, s5 = 0.f, s6 = 0.f, s7 = 0.f;
        int j = 0;
        for (; j + 8 <= cnt; j += 8) {
            int i0 = sp[j],     i1 = sp[j + 1], i2 = sp[j + 2], i3 = sp[j + 3];
            int i4 = sp[j + 4], i5 = sp[j + 5], i6 = sp[j + 6], i7 = sp[j + 7];
            uint4 v0 = xb4[i0 * 16 + l16];
            uint4 v1 = xb4[i1 * 16 + l16];
            uint4 v2 = xb4[i2 * 16 + l16];
            uint4 v3 = xb4[i3 * 16 + l16];
            uint4 v4 = xb4[i4 * 16 + l16];
            uint4 v5 = xb4[i5 * 16 + l16];
            uint4 v6 = xb4[i6 * 16 + l16];
            uint4 v7 = xb4[i7 * 16 + l16];
            ACC8(v0); ACC8(v1); ACC8(v2); ACC8(v3);
            ACC8(v4); ACC8(v5); ACC8(v6); ACC8(v7);
        }
        for (; j + 4 <= cnt; j += 4) {
            int i0 = sp[j], i1 = sp[j + 1], i2 = sp[j + 2], i3 = sp[j + 3];
            uint4 v0 = xb4[i0 * 16 + l16];
            uint4 v1 = xb4[i1 * 16 + l16];
            uint4 v2 = xb4[i2 * 16 + l16];
            uint4 v3 = xb4[i3 * 16 + l16];
            ACC8(v0); ACC8(v1); ACC8(v2); ACC8(v3);
        }
        for (; j < cnt; j++) {
            uint4 v = xb4[sp[j] * 16 + l16];
            ACC8(v);
        }
        float rd = 1.0f / fmaxf((float)cnt, 1.0f);
        uint4 o;
        o.x = f2bf2(s0 * rd, s1 * rd);
        o.y = f2bf2(s2 * rd, s3 * rd);
        o.z = f2bf2(s4 * rd, s5 * rd);
        o.w = f2bf2(s6 * rd, s7 * rd);
        *(uint4*)&sA[nl][l16 * 8] = o;
    }
    __syncthreads();

    const int col = lane & 15, quad = lane >> 4;

    // ---- phase A: h = relu(A @ W1^T + bl1), N=256, K=256 ----
    floatx4 acc[2][4];
    const floatx4 zero = {0.f, 0.f, 0.f, 0.f};
#pragma unroll
    for (int mt = 0; mt < 2; mt++)
#pragma unroll
        for (int nt = 0; nt < 4; nt++) acc[mt][nt] = zero;

    const short8* w1base = (const short8*)W1s + wave * 2048 + lane;
#pragma unroll
    for (int ks = 0; ks < 8; ks++) {
        short8 a0 = *(const short8*)&sA[col][ks * 32 + quad * 8];
        short8 a1 = *(const short8*)&sA[16 + col][ks * 32 + quad * 8];
#pragma unroll
        for (int nt = 0; nt < 4; nt++) {
            short8 b = w1base[(nt * 8 + ks) * 64];
            acc[0][nt] = MFMA16(a0, b, acc[0][nt]);
            acc[1][nt] = MFMA16(a1, b, acc[1][nt]);
        }
    }

#pragma unroll
    for (int nt = 0; nt < 4; nt++) {
        int out = (wave * 4 + nt) * 16 + col;
        float bias = bl1[out];
#pragma unroll
        for (int mt = 0; mt < 2; mt++)
#pragma unroll
            for (int r = 0; r < 4; r++)
                sH[mt * 16 + quad * 4 + r][out] = f2bf(fmaxf(acc[mt][nt][r] + bias, 0.f));
    }
    __syncthreads();

    // ---- phase B: [z2|r2] = h @ W2^T, N=128, K=256 ----
    floatx4 acc2[2][2];
#pragma unroll
    for (int mt = 0; mt < 2; mt++)
#pragma unroll
        for (int nt = 0; nt < 2; nt++) acc2[mt][nt] = zero;

    const short8* w2base = (const short8*)W2s + wave * 1024 + lane;
#pragma unroll
    for (int ks = 0; ks < 8; ks++) {
        short8 h0 = *(const short8*)&sH[col][ks * 32 + quad * 8];
        short8 h1 = *(const short8*)&sH[16 + col][ks * 32 + quad * 8];
#pragma unroll
        for (int nt = 0; nt < 2; nt++) {
            short8 b = w2base[(nt * 8 + ks) * 64];
            acc2[0][nt] = MFMA16(h0, b, acc2[0][nt]);
            acc2[1][nt] = MFMA16(h1, b, acc2[1][nt]);
        }
    }

#pragma unroll
    for (int nt = 0; nt < 2; nt++) {
        int out = (wave * 2 + nt) * 16 + col;
#pragma unroll
        for (int mt = 0; mt < 2; mt++)
#pragma unroll
            for (int r = 0; r < 4; r++) {
                int node = node0 + mt * 16 + quad * 4 + r;
                float v = acc2[mt][nt][r];
                if (out < 64) z2bf[node * 64 + out] = f2bf(v);
                else          embOut[node * 64 + (out - 64)] = v;
            }
    }
}

// ---------------- FUSED decoder: gather emb (eighth-wave/node) + MFMA -------
// Phase 0: eighth-wave (8 lanes x uint4 = 128B z2 row) per node, 32 nodes =
//          4 waves x 8 eighths; finalize emb fp32 and pack bf16 into sE.
//          Eliminates the embbf round trip (25.6 MB).
__global__ __launch_bounds__(256, 4) void fused_decoder(
        const uint4* __restrict__ z4, const int* __restrict__ srcS,
        const int* __restrict__ offs, const int* __restrict__ degI,
        const float* __restrict__ bl2, float* __restrict__ emb,
        const unsigned short* __restrict__ F1s, const float* __restrict__ fc1b,
        const unsigned short* __restrict__ F2s, const float* __restrict__ fc2b,
        float* __restrict__ recon) {
    __shared__ unsigned short sE[MT][72];
    __shared__ unsigned short sH[MT][264];
    const int tid = threadIdx.x;
    const int node0 = blockIdx.x * MT;
    const int wave = tid >> 6, lane = tid & 63;
    const int g = lane >> 3, l8 = lane & 7;

    {
        const int nl = wave * 8 + g;      // 0..31
        const int n = node0 + nl;
        const int start = offs[n], cnt = degI[n];
        const int* sp = srcS + start;
        float s0 = 0.f, s1 = 0.f, s2 = 0.f, s3 = 0.f;
        float s4 = 0.f, s5 = 0.f, s6 = 0.f, s7 = 0.f;
        int j = 0;
        for (; j + 8 <= cnt; j += 8) {
            int i0 = sp[j],     i1 = sp[j + 1], i2 = sp[j + 2], i3 = sp[j + 3];
            int i4 = sp[j + 4], i5 = sp[j + 5], i6 = sp[j + 6], i7 = sp[j + 7];
            uint4 v0 = z4[i0 * 8 + l8];
            uint4 v1 = z4[i1 * 8 + l8];
            uint4 v2 = z4[i2 * 8 + l8];
            uint4 v3 = z4[i3 * 8 + l8];
            uint4 v4 = z4[i4 * 8 + l8];
            uint4 v5 = z4[i5 * 8 + l8];
            uint4 v6 = z4[i6 * 8 + l8];
            uint4 v7 = z4[i7 * 8 + l8];
            ACC8(v0); ACC8(v1); ACC8(v2); ACC8(v3);
            ACC8(v4); ACC8(v5); ACC8(v6); ACC8(v7);
        }
        for (; j + 4 <= cnt; j += 4) {
            int i0 = sp[j], i1 = sp[j + 1], i2 = sp[j + 2], i3 = sp[j + 3];
            uint4 v0 = z4[i0 * 8 + l8];
            uint4 v1 = z4[i1 * 8 + l8];
            uint4 v2 = z4[i2 * 8 + l8];
            uint4 v3 = z4[i3 * 8 + l8];
            ACC8(v0); ACC8(v1); ACC8(v2); ACC8(v3);
        }
        for (; j < cnt; j++) {
            uint4 v = z4[sp[j] * 8 + l8];
            ACC8(v);
        }
        float rd = 1.0f / fmaxf((float)cnt, 1.0f);
        float4 ra = *(const float4*)&emb[n * 64 + l8 * 8];
        float4 rb = *(const float4*)&emb[n * 64 + l8 * 8 + 4];
        float4 ba = *(const float4*)&bl2[l8 * 8];
        float4 bb = *(const float4*)&bl2[l8 * 8 + 4];
        float e0 = s0 * rd + ba.x + ra.x;
        float e1 = s1 * rd + ba.y + ra.y;
        float e2 = s2 * rd + ba.z + ra.z;
        float e3 = s3 * rd + ba.w + ra.w;
        float e4 = s4 * rd + bb.x + rb.x;
        float e5 = s5 * rd + bb.y + rb.y;
        float e6 = s6 * rd + bb.z + rb.z;
        float e7 = s7 * rd + bb.w + rb.w;
        float4 wa = {e0, e1, e2, e3};
        float4 wb = {e4, e5, e6, e7};
        *(float4*)&emb[n * 64 + l8 * 8] = wa;
        *(float4*)&emb[n * 64 + l8 * 8 + 4] = wb;
        uint4 o;
        o.x = f2bf2(e0, e1);
        o.y = f2bf2(e2, e3);
        o.z = f2bf2(e4, e5);
        o.w = f2bf2(e6, e7);
        *(uint4*)&sE[nl][l8 * 8] = o;
    }
    __syncthreads();

    const int col = lane & 15, quad = lane >> 4;

    // ---- phase A: hid = relu(emb @ fc1^T + fc1b), N=256, K=64 ----
    floatx4 acc[2][4];
    const floatx4 zero = {0.f, 0.f, 0.f, 0.f};
#pragma unroll
    for (int mt = 0; mt < 2; mt++)
#pragma unroll
        for (int nt = 0; nt < 4; nt++) acc[mt][nt] = zero;

    const short8* f1base = (const short8*)F1s + wave * 512 + lane;
#pragma unroll
    for (int ks = 0; ks < 2; ks++) {
        short8 a0 = *(const short8*)&sE[col][ks * 32 + quad * 8];
        short8 a1 = *(const short8*)&sE[16 + col][ks * 32 + quad * 8];
#pragma unroll
        for (int nt = 0; nt < 4; nt++) {
            short8 b = f1base[(nt * 2 + ks) * 64];
            acc[0][nt] = MFMA16(a0, b, acc[0][nt]);
            acc[1][nt] = MFMA16(a1, b, acc[1][nt]);
        }
    }

#pragma unroll
    for (int nt = 0; nt < 4; nt++) {
        int out = (wave * 4 + nt) * 16 + col;
        float bias = fc1b[out];
#pragma unroll
        for (int mt = 0; mt < 2; mt++)
#pragma unroll
            for (int r = 0; r < 4; r++)
                sH[mt * 16 + quad * 4 + r][out] = f2bf(fmaxf(acc[mt][nt][r] + bias, 0.f));
    }
    __syncthreads();

    // ---- phase B: recon = hid @ fc2^T + fc2b, N=128, K=256 ----
    floatx4 acc2[2][2];
#pragma unroll
    for (int mt = 0; mt < 2; mt++)
#pragma unroll
        for (int nt = 0; nt < 2; nt++) acc2[mt][nt] = zero;

    const short8* f2base = (const short8*)F2s + wave * 1024 + lane;
#pragma unroll
    for (int ks = 0; ks < 8; ks++) {
        short8 h0 = *(const short8*)&sH[col][ks * 32 + quad * 8];
        short8 h1 = *(const short8*)&sH[16 + col][ks * 32 + quad * 8];
#pragma unroll
        for (int nt = 0; nt < 2; nt++) {
            short8 b = f2base[(nt * 8 + ks) * 64];
            acc2[0][nt] = MFMA16(h0, b, acc2[0][nt]);
            acc2[1][nt] = MFMA16(h1, b, acc2[1][nt]);
        }
    }

#pragma unroll
    for (int nt = 0; nt < 2; nt++) {
        int out = (wave * 2 + nt) * 16 + col;
        float bias = fc2b[out];
#pragma unroll
        for (int mt = 0; mt < 2; mt++)
#pragma unroll
            for (int r = 0; r < 4; r++) {
                int node = node0 + mt * 16 + quad * 4 + r;
                recon[node * 128 + out] = acc2[mt][nt][r] + bias;
            }
    }
}

extern "C" void kernel_launch(void* const* d_in, const int* in_sizes, int n_in,
                              void* d_out, int out_size, void* d_ws, size_t ws_size,
                              hipStream_t stream) {
    const float* x    = (const float*)d_in[0];
    const int*   ei   = (const int*)d_in[1];
    const int E = in_sizes[1] / 2;
    const int* src = ei;
    const int* dst = ei + E;
    const float* Wl1  = (const float*)d_in[2];
    const float* bl1  = (const float*)d_in[3];
    const float* Wr1  = (const float*)d_in[4];
    const float* Wl2  = (const float*)d_in[5];
    const float* bl2  = (const float*)d_in[6];
    const float* Wr2  = (const float*)d_in[7];
    const float* fc1W = (const float*)d_in[8];
    const float* fc1b = (const float*)d_in[9];
    const float* fc2W = (const float*)d_in[10];
    const float* fc2b = (const float*)d_in[11];

    float* out   = (float*)d_out;
    float* emb   = out;                           // N*64
    float* recon = out + (size_t)N_NODES * D_E;   // N*128

    // workspace layout (512-aligned offsets)
    char* ws = (char*)d_ws;
    unsigned short* xbf    = (unsigned short*)(ws);             // 25,600,000 B
    // (ws+25,600,000 region: pairs buffer, 6.4MB)
    unsigned short* z2bf   = (unsigned short*)(ws + 51200000);  // 12,800,000 B
    int* degI   = (int*)(ws + 76800000);                        //    400,000 B
    int* offs   = (int*)(ws + 77200384);                        //    400,000 B
    int* gcur      = (int*)(ws + 77600768);                     // 196*64 B padded counters
    int* bucketCnt = (int*)(ws + 77617152);                     // 196*64 B padded counters
    int* bucketOffs= (int*)(ws + 77633536);                     // 197*4 B
    int* srcS   = (int*)(ws + 78001664);                        //  6,400,000 B
    unsigned short* W1s = (unsigned short*)(ws + 84401664);     //    131,072 B
    unsigned short* W2s = (unsigned short*)(ws + 84532736);     //     65,536 B
    unsigned short* F1s = (unsigned short*)(ws + 84598272);     //     32,768 B
    unsigned short* F2s = (unsigned short*)(ws + 84631040);     //     65,536 B
    // end 84,696,576 B
    unsigned* pairs = (unsigned*)(ws + 25600000);

    // gcur + bucketCnt are contiguous: one memset
    hipMemsetAsync(gcur, 0, 32768, stream);

    convert_weights<<<(147456 + 255) / 256, 256, 0, stream>>>(
        Wl1, Wr1, Wl2, Wr2, fc1W, fc2W, W1s, W2s, F1s, F2s);
    convert_x<<<(N_NODES * 32 + 255) / 256, 256, 0, stream>>>(
        (const float4*)x, (uint2*)xbf, N_NODES * 32);

    // counting sort of edges by dst (bucket hist + radix two-pass)
    const int nChunks = (E + CHUNK - 1) / CHUNK;  // 196 at E=1.6M
    bucket_hist<<<nChunks, RCR_T, 0, stream>>>(dst, bucketCnt, E);
    bucket_scan<<<1, 256, 0, stream>>>(bucketCnt, bucketOffs);
    radix_count_reserve<<<nChunks, RCR_T, 0, stream>>>(
        src, dst, bucketOffs, gcur, pairs, E);
    radix_scatter2<<<NBUCK, 512, 0, stream>>>(
        pairs, bucketOffs, degI, offs, srcS);

    // layer 1: fused gather-mean + MFMA (32 nodes/block)
    fused_layer1<<<N_NODES / MT, 256, 0, stream>>>(
        (const uint4*)xbf, srcS, offs, degI, W1s, bl1, W2s, z2bf, emb);

    // layer 2 + decoder: fused gather-emb + MFMA (32 nodes/block)
    fused_decoder<<<N_NODES / MT, 256, 0, stream>>>(
        (const uint4*)z2bf, srcS, offs, degI, bl2, emb,
        F1s, fc1b, F2s, fc2b, recon);
}